// Round 2
// baseline (461.531 us; speedup 1.0000x reference)
//
#include <hip/hip_runtime.h>
#include <hip/hip_bf16.h>

// Problem constants
#define BB 8
#define NN 128
#define CC 256
#define HFD 160
#define WFD 160
#define SS 7
#define REGION_OUT_ELEMS (8*128*256*49)   // 12,845,056

typedef short short8 __attribute__((ext_vector_type(8)));
typedef float f32x4  __attribute__((ext_vector_type(4)));

// ---------------------------------------------------------------------------
// K0: convert proj_w [o][c] fp32 -> bf16, row-major (A-operand friendly).
// ---------------------------------------------------------------------------
__global__ __launch_bounds__(256) void k0_convert_w(const float* __restrict__ W,
                                                    __hip_bfloat16* __restrict__ Wb) {
    int o = blockIdx.x;
    int c = threadIdx.x;
    Wb[o * CC + c] = __float2bfloat16(W[o * CC + c]);
}

// ---------------------------------------------------------------------------
// K1: fused transpose + row-cumsum.
//   in : fm[b][c][h][w]   (w fastest)
//   out: R[b][h][w][c]    (c fastest), R = cumsum of fm along w
// ---------------------------------------------------------------------------
__global__ __launch_bounds__(256) void k1_rowsum_transpose(const float* __restrict__ fm,
                                                           float* __restrict__ R) {
    int bid = blockIdx.x;            // ((b*160)+h)*4 + cq
    int cq  = bid & 3;
    int bh  = bid >> 2;
    int h   = bh % HFD;
    int b   = bh / HFD;
    int c0  = cq * 64;
    int t   = threadIdx.x;

    __shared__ float tile[64][161];
    __shared__ float segsum[64][5];

    #pragma unroll
    for (int it = 0; it < 10; ++it) {
        int vid = it * 256 + t;              // 0..2559
        int c_l = vid / 40;
        int wq  = vid - c_l * 40;            // float4 index within row
        f32x4 v = __builtin_nontemporal_load(
            (const f32x4*)(fm + (((size_t)(b * CC + c0 + c_l)) * HFD + h) * WFD + wq * 4));
        tile[c_l][wq * 4 + 0] = v.x;
        tile[c_l][wq * 4 + 1] = v.y;
        tile[c_l][wq * 4 + 2] = v.z;
        tile[c_l][wq * 4 + 3] = v.w;
    }
    __syncthreads();

    int seg = t >> 6;        // 0..3
    int row = t & 63;        // 0..63
    {
        float s = 0.f;
        int w0 = seg * 40;
        #pragma unroll 8
        for (int k = 0; k < 40; ++k) {
            s += tile[row][w0 + k];
            tile[row][w0 + k] = s;
        }
        segsum[row][seg] = s;
    }
    __syncthreads();
    if (t < 64) {
        float a0 = segsum[t][0];
        float a1 = a0 + segsum[t][1];
        float a2 = a1 + segsum[t][2];
        segsum[t][1] = a0;
        segsum[t][2] = a1;
        segsum[t][3] = a2;
    }
    __syncthreads();
    if (seg > 0) {
        float off = segsum[row][seg];
        int w0 = seg * 40;
        #pragma unroll 8
        for (int k = 0; k < 40; ++k) tile[row][w0 + k] += off;
    }
    __syncthreads();

    size_t obase = (((size_t)b * HFD + h) * WFD) * CC + c0;
    #pragma unroll
    for (int it = 0; it < 10; ++it) {
        int vid = it * 256 + t;
        int w   = vid >> 4;        // 0..159
        int cg  = vid & 15;        // c = 4*cg
        float4 o;
        o.x = tile[cg * 4 + 0][w];
        o.y = tile[cg * 4 + 1][w];
        o.z = tile[cg * 4 + 2][w];
        o.w = tile[cg * 4 + 3][w];
        *(float4*)(R + obase + (size_t)w * CC + cg * 4) = o;
    }
}

// ---------------------------------------------------------------------------
// K2: in-place column cumsum along h in c-fastest layout.
// One 256-thread WG per (b, w); thread owns ONE channel (scalar RMW).
// ---------------------------------------------------------------------------
__global__ __launch_bounds__(256) void k2_colsum(float* __restrict__ I) {
    int w = blockIdx.x % WFD;
    int b = blockIdx.x / WFD;
    int c = threadIdx.x;
    float* p = I + (((size_t)b * HFD) * WFD + w) * CC + c;   // h = 0
    const size_t stride = (size_t)WFD * CC;                   // per-h stride (floats)
    float s = 0.f;
    #pragma unroll 16
    for (int h = 0; h < HFD; ++h) {
        float v = p[(size_t)h * stride];
        s += v;
        p[(size_t)h * stride] = s;
    }
}

// ---------------------------------------------------------------------------
// K3a: gather-only. Per (b,n): compute the 49 cell means from the integral
// image, convert to bf16, write Pm[bn][64][256] (cells 49..63 zero pad).
// No LDS -> 32 waves/CU in-flight; pure latency-pipelined L3 gather.
// 512 threads: t = (half, c); half 0 -> cells 0..24, half 1 -> cells 25..48.
// half is wave-uniform (no divergence).
// ---------------------------------------------------------------------------
__global__ __launch_bounds__(512) void k3a_gather(
        const float* __restrict__ I, const float* __restrict__ bboxes,
        const int* __restrict__ ih_p, const int* __restrict__ iw_p,
        __hip_bfloat16* __restrict__ Pm, float* __restrict__ out) {
    int bn = blockIdx.x;         // b*128 + n
    int b  = bn >> 7;
    int t  = threadIdx.x;
    int c  = t & 255;
    int half = t >> 8;

    float bx1 = bboxes[bn * 4 + 0];
    float by1 = bboxes[bn * 4 + 1];
    float bx2 = bboxes[bn * 4 + 2];
    float by2 = bboxes[bn * 4 + 3];
    float sx = (float)WFD / (float)iw_p[0];
    float sy = (float)HFD / (float)ih_p[0];

    int x1 = min(max((int)floorf(bx1 * sx), 0), WFD - 1);
    int y1 = min(max((int)floorf(by1 * sy), 0), HFD - 1);
    int x2 = min(max((int)floorf(bx2 * sx), x1 + 1), WFD);
    int y2 = min(max((int)floorf(by2 * sy), y1 + 1), HFD);
    int Lx = x2 - x1, Ly = y2 - y1;

    int rs[SS], re[SS], cs[SS], ce[SS];
    #pragma unroll
    for (int i = 0; i < SS; ++i) {
        rs[i] = y1 + (i * Ly) / SS;
        re[i] = y1 + ((i + 1) * Ly + SS - 1) / SS;
        cs[i] = x1 + (i * Lx) / SS;
        ce[i] = x1 + ((i + 1) * Lx + SS - 1) / SS;
    }

    const size_t Ib = (size_t)b * HFD * WFD * CC;
    __hip_bfloat16* pmb = Pm + (size_t)bn * 64 * CC;

#define GATHER_CELL(cell)                                                        \
    {                                                                            \
        const int i_ = (cell) / SS, j_ = (cell) % SS;                            \
        int r0 = rs[i_] - 1, r1 = re[i_] - 1;                                    \
        int c0 = cs[j_] - 1, c1 = ce[j_] - 1;                                    \
        float br = I[Ib + ((size_t)(r1 * WFD + c1)) * CC + c];                   \
        float tr = (r0 >= 0) ? I[Ib + ((size_t)(r0 * WFD + c1)) * CC + c] : 0.f; \
        float bl = (c0 >= 0) ? I[Ib + ((size_t)(r1 * WFD + c0)) * CC + c] : 0.f; \
        float tl = (r0 >= 0 && c0 >= 0) ? I[Ib + ((size_t)(r0 * WFD + c0)) * CC + c] : 0.f; \
        float cnt = (float)(re[i_] - rs[i_]) * (float)(ce[j_] - cs[j_]);         \
        pmb[(cell) * CC + c] = __float2bfloat16((br - tr - bl + tl) / cnt);      \
    }

    if (half == 0) {
        #pragma unroll
        for (int k = 0; k < 25; ++k) GATHER_CELL(k);
    } else {
        #pragma unroll
        for (int k = 25; k < 49; ++k) GATHER_CELL(k);
        // zero the pad cells 49..63
        __hip_bfloat16 z = __float2bfloat16(0.f);
        #pragma unroll
        for (int r = 49; r < 64; ++r) pmb[r * CC + c] = z;
    }
#undef GATHER_CELL

    if (t == 0) {
        __builtin_nontemporal_store((bx2 - bx1) * (by2 - by1), &out[REGION_OUT_ELEMS + bn]);
    }
}

// ---------------------------------------------------------------------------
// K3b: GEMM-only. out[bn][o][cell] = sum_c W[o][c]*Pm[bn][cell][c] + bias[o].
// M=256 (o), N=64 (49 + pad), K=256. A,B frags loaded directly from global
// (both L2-hot: Wb everywhere, Pm written by same-XCD K3a block).
// No LDS, no barriers.
// ---------------------------------------------------------------------------
__global__ __launch_bounds__(256) void k3b_gemm(
        const __hip_bfloat16* __restrict__ Wb, const __hip_bfloat16* __restrict__ Pm,
        const float* __restrict__ bias, float* __restrict__ out) {
    int bn = blockIdx.x;
    int t  = threadIdx.x;
    const int lane = t & 63;
    const int wv   = t >> 6;
    const int ln   = lane & 15;
    const int quad = lane >> 4;
    const int ob0  = wv * 64;

    const short* A  = (const short*)Wb;
    const short* Bm = (const short*)(Pm + (size_t)bn * 64 * CC);

    f32x4 z = {0.f, 0.f, 0.f, 0.f};
    f32x4 acc[4][4];
    #pragma unroll
    for (int mt = 0; mt < 4; ++mt)
        #pragma unroll
        for (int nt = 0; nt < 4; ++nt) acc[mt][nt] = z;

    #pragma unroll
    for (int k0 = 0; k0 < CC; k0 += 32) {
        short8 a[4], bf[4];
        #pragma unroll
        for (int mt = 0; mt < 4; ++mt)
            a[mt] = *(const short8*)(A + (ob0 + mt * 16 + ln) * CC + k0 + quad * 8);
        #pragma unroll
        for (int nt = 0; nt < 4; ++nt)
            bf[nt] = *(const short8*)(Bm + (nt * 16 + ln) * CC + k0 + quad * 8);
        #pragma unroll
        for (int mt = 0; mt < 4; ++mt)
            #pragma unroll
            for (int nt = 0; nt < 4; ++nt)
                acc[mt][nt] = __builtin_amdgcn_mfma_f32_16x16x32_bf16(a[mt], bf[nt], acc[mt][nt], 0, 0, 0);
    }

    // epilogue: D layout col(cell)=lane&15, row(o)=quad*4+reg
    size_t obase = (size_t)bn * CC * 49;
    #pragma unroll
    for (int mt = 0; mt < 4; ++mt) {
        f32x4 bv = *(const f32x4*)(bias + ob0 + mt * 16 + quad * 4);
        #pragma unroll
        for (int nt = 0; nt < 4; ++nt) {
            int cell = nt * 16 + ln;
            if (cell < 49) {
                #pragma unroll
                for (int reg = 0; reg < 4; ++reg) {
                    int o = ob0 + mt * 16 + quad * 4 + reg;
                    __builtin_nontemporal_store(acc[mt][nt][reg] + bv[reg],
                                                &out[obase + (size_t)o * 49 + cell]);
                }
            }
        }
    }
}

// ---------------------------------------------------------------------------
extern "C" void kernel_launch(void* const* d_in, const int* in_sizes, int n_in,
                              void* d_out, int out_size, void* d_ws, size_t ws_size,
                              hipStream_t stream) {
    const float* fm     = (const float*)d_in[0];
    const float* bboxes = (const float*)d_in[1];
    const float* W      = (const float*)d_in[2];
    const float* bias   = (const float*)d_in[3];
    const int*   ih     = (const int*)d_in[4];
    const int*   iw     = (const int*)d_in[5];
    float* out = (float*)d_out;

    __hip_bfloat16* Wb = (__hip_bfloat16*)d_ws;                   // 256*256 bf16 = 128 KB
    float* I = (float*)((char*)d_ws + (size_t)CC * CC * 2 + 256); // integral image, c-fastest
    I = (float*)(((uintptr_t)I + 1023) & ~(uintptr_t)1023);
    // Pm after I: 1024 * 64 * 256 bf16 = 33.5 MB
    __hip_bfloat16* Pm = (__hip_bfloat16*)((char*)I + (size_t)BB * HFD * WFD * CC * 4);
    Pm = (__hip_bfloat16*)(((uintptr_t)Pm + 1023) & ~(uintptr_t)1023);

    k0_convert_w<<<CC, 256, 0, stream>>>(W, Wb);
    k1_rowsum_transpose<<<BB * HFD * 4, 256, 0, stream>>>(fm, I);
    k2_colsum<<<BB * WFD, 256, 0, stream>>>(I);
    k3a_gather<<<BB * NN, 512, 0, stream>>>(I, bboxes, ih, iw, Pm, out);
    k3b_gemm<<<BB * NN, 256, 0, stream>>>(Wb, Pm, bias, out);
}